// Round 2
// baseline (379.804 us; speedup 1.0000x reference)
//
#include <hip/hip_runtime.h>
#include <math.h>

#define D_MODEL 1024
#define NQS 2048
#define NKS 2048
#define BATCH 4

typedef __attribute__((ext_vector_type(8))) short bf16x8;
typedef __attribute__((ext_vector_type(4))) float f32x4;

#define AS1 __attribute__((address_space(1)))
#define AS3 __attribute__((address_space(3)))

__device__ __forceinline__ unsigned short f2bf(float f) {
  unsigned u = __builtin_bit_cast(unsigned, f);
  u = (u + 0x7FFF + ((u >> 16) & 1)) >> 16;  // RNE
  return (unsigned short)u;
}
__device__ __forceinline__ float bf2f(unsigned short s) {
  return __builtin_bit_cast(float, ((unsigned)s) << 16);
}

// ---------------- fp32 -> bf16 converts (z-merged) ----------------
__global__ __launch_bounds__(256) void cvt3_k(
    const float* __restrict__ s0, const float* __restrict__ s1,
    const float* __restrict__ s2, short* __restrict__ d0,
    short* __restrict__ d1, short* __restrict__ d2, int n8)
{
  const int z = blockIdx.z;
  const float* src = z == 0 ? s0 : (z == 1 ? s1 : s2);
  short* dst = z == 0 ? d0 : (z == 1 ? d1 : d2);
  int i = blockIdx.x * 256 + threadIdx.x;
  if (i >= n8) return;
  const float4 a = *(const float4*)&src[(long)i * 8];
  const float4 b = *(const float4*)&src[(long)i * 8 + 4];
  bf16x8 o;
  o[0] = (short)f2bf(a.x); o[1] = (short)f2bf(a.y);
  o[2] = (short)f2bf(a.z); o[3] = (short)f2bf(a.w);
  o[4] = (short)f2bf(b.x); o[5] = (short)f2bf(b.y);
  o[6] = (short)f2bf(b.z); o[7] = (short)f2bf(b.w);
  *(bf16x8*)&dst[(long)i * 8] = o;
}

// ---------------- 128x128 legacy tile body (kept for out-GEMM) -----------
__device__ __forceinline__ void gemm_tile_body(
    const short* __restrict__ Ab, const short* __restrict__ Bb,
    const float* __restrict__ bias, float bscale, float* __restrict__ Cf,
    short* __restrict__ Cbf, int N, int K, int gm, int gn)
{
  __shared__ short As[2][128 * 32];
  __shared__ short Bs[2][128 * 32];
  const int t = threadIdx.x;
  const int lane = t & 63, w = t >> 6;
  const int wm = w >> 1, wn = w & 1;

  const int srow = lane >> 2, sq = lane & 3;
  const short* gA0 = Ab + (long)(gm + w * 32 + srow) * K + sq * 8;
  const short* gA1 = Ab + (long)(gm + w * 32 + 16 + srow) * K + sq * 8;
  const short* gB0 = Bb + (long)(gn + w * 32 + srow) * K + sq * 8;
  const short* gB1 = Bb + (long)(gn + w * 32 + 16 + srow) * K + sq * 8;
  const int seg0 = (w * 2 + 0) * 512, seg1 = (w * 2 + 1) * 512;

  const int frow = lane & 15, fq = lane >> 4;

  f32x4 acc[4][4] = {};

  for (int k0 = 0; k0 < K; k0 += 64) {
#pragma unroll
    for (int p = 0; p < 2; ++p) {
      const int ko = k0 + p * 32;
      __builtin_amdgcn_global_load_lds((const AS1 void*)(gA0 + ko),
                                       (AS3 void*)(&As[p][seg0]), 16, 0, 0);
      __builtin_amdgcn_global_load_lds((const AS1 void*)(gA1 + ko),
                                       (AS3 void*)(&As[p][seg1]), 16, 0, 0);
      __builtin_amdgcn_global_load_lds((const AS1 void*)(gB0 + ko),
                                       (AS3 void*)(&Bs[p][seg0]), 16, 0, 0);
      __builtin_amdgcn_global_load_lds((const AS1 void*)(gB1 + ko),
                                       (AS3 void*)(&Bs[p][seg1]), 16, 0, 0);
    }
    __syncthreads();
#pragma unroll
    for (int p = 0; p < 2; ++p) {
      bf16x8 af[4], bfm[4];
#pragma unroll
      for (int mi = 0; mi < 4; ++mi)
        af[mi] =
            *(const bf16x8*)&As[p][(wm * 64 + mi * 16 + frow) * 32 + fq * 8];
#pragma unroll
      for (int ni = 0; ni < 4; ++ni)
        bfm[ni] =
            *(const bf16x8*)&Bs[p][(wn * 64 + ni * 16 + frow) * 32 + fq * 8];
#pragma unroll
      for (int mi = 0; mi < 4; ++mi)
#pragma unroll
        for (int ni = 0; ni < 4; ++ni)
          acc[mi][ni] = __builtin_amdgcn_mfma_f32_16x16x32_bf16(
              af[mi], bfm[ni], acc[mi][ni], 0, 0, 0);
    }
    __syncthreads();
  }

  float bb[4];
#pragma unroll
  for (int ni = 0; ni < 4; ++ni)
    bb[ni] = bias ? bias[gn + wn * 64 + ni * 16 + frow] * bscale : 0.f;

#pragma unroll
  for (int mi = 0; mi < 4; ++mi) {
#pragma unroll
    for (int r = 0; r < 4; ++r) {
      const long row = gm + wm * 64 + mi * 16 + fq * 4 + r;
#pragma unroll
      for (int ni = 0; ni < 4; ++ni) {
        const long col = gn + wn * 64 + ni * 16 + frow;
        float v = acc[mi][ni][r] + bb[ni];
        if (Cf) Cf[row * (long)N + col] = v;
        else    Cbf[row * (long)N + col] = (short)f2bf(v);
      }
    }
  }
}

__global__ __launch_bounds__(256, 4) void mfma_abt_k(
    const short* __restrict__ A, const short* __restrict__ B,
    const float* __restrict__ bias, float bscale, float* __restrict__ Cf,
    short* __restrict__ Cbf, int N, int K, long sA, long sB, long sC,
    long sBias, int swap)
{
  const int bz = blockIdx.z;
  const int gm = (swap ? blockIdx.x : blockIdx.y) * 128;
  const int gn = (swap ? blockIdx.y : blockIdx.x) * 128;
  gemm_tile_body(A + (long)bz * sA, B + (long)bz * sB,
                 bias ? bias + (long)bz * sBias : nullptr, bscale,
                 Cf ? Cf + (long)bz * sC : nullptr,
                 Cbf ? Cbf + (long)bz * sC : nullptr, N, K, gm, gn);
}

// ================= 256x256 8-phase counted-vmcnt GEMM (T2+T3+T4+T5) =======
// A:[M,K] bf16 rm, B:[N,K] bf16 rm, C = A*B^T (+ bias[col]*bscale).
// 512 thr = 8 waves (2Mx4N); per-wave C = 128x64. BK=64. LDS = 128 KiB.
// Swizzle: LDS[row][slot] = global[row][slot^(row&7)] via pre-swizzled
// GLOBAL source (linear gload_lds dest, m173 rule) + swizzled ds_read.
//
// LIVENESS (fixed after r1 race): halves are read by DIFFERENT waves in
// parallel, so As[PI][0] AND As[PI][1] stay live until P3-END (wm=0 reads
// half0 rows 0-63 @P1, rows 64-127 @P3; wm=1 same on half1); Bs[PI][*]
// live until P2-END. Next-parity regions hold tile tau+1 (fully live).
// => NOTHING may be staged at P1/P2. Stage schedule:
//   P3: B0(tau+2), B1(tau+2) -> Bs[PI]   (issued after P2-END barrier)
//   P4: A0(tau+2), A1(tau+2) -> As[PI]   (issued after P3-END barrier)
// Steady state: entering tile tau, tau+1's 8 loads in flight; tile tau
// issues 8 (tau+2); vmcnt(8) @P4 confirms tau+1's 8 (oldest). Tail
// (tau >= NT-2): no issues, vmcnt(0).

#define STAGE_HALF(gbase, hoff, kofs, region)                                \
  do {                                                                       \
    __builtin_amdgcn_global_load_lds(                                        \
        (const AS1 void*)((gbase) + (long)(hoff) * K + (kofs)),              \
        (AS3 void*)((region) + w * 512), 16, 0, 0);                          \
    __builtin_amdgcn_global_load_lds(                                        \
        (const AS1 void*)((gbase) + (long)((hoff) + 64) * K + (kofs)),       \
        (AS3 void*)((region) + 4096 + w * 512), 16, 0, 0);                   \
  } while (0)

#define PHASE_TOP()                                  \
  __builtin_amdgcn_s_barrier();                      \
  asm volatile("s_waitcnt lgkmcnt(0)" ::: "memory"); \
  __builtin_amdgcn_sched_barrier(0);                 \
  __builtin_amdgcn_s_setprio(1)

#define PHASE_END()                 \
  __builtin_amdgcn_s_setprio(0);    \
  __builtin_amdgcn_s_barrier();     \
  __builtin_amdgcn_sched_barrier(0)

template <int PI>
__device__ __forceinline__ void tile4(short (&As)[2][2][8192],
                                      short (&Bs)[2][2][8192],
                                      const short* gA, const short* gB,
                                      f32x4 (&acc)[8][4], int tau, int K,
                                      int w, int wm, int wn, int frow,
                                      int fq, int fr7)
{
  const int kt2 = (tau + 2) << 6;
  const short* Ah = &As[PI][wm][0];
  const short* Bh = &Bs[PI][wn >> 1][0];
  const int bofs = (wn & 1) * 64;
  const int x0 = (fq ^ fr7) * 8;        // kk=0 swizzled slot offset (shorts)
  const int x1 = ((4 + fq) ^ fr7) * 8;  // kk=1

  bf16x8 a0[4][2], a1[4][2], b0[2][2], b1[2][2];

  // ---- P1: quadrant (0,0); no stage (all LDS regions live) ----
#pragma unroll
  for (int mi = 0; mi < 4; ++mi) {
    a0[mi][0] = *(const bf16x8*)&Ah[(mi * 16 + frow) * 64 + x0];
    a0[mi][1] = *(const bf16x8*)&Ah[(mi * 16 + frow) * 64 + x1];
  }
#pragma unroll
  for (int ni = 0; ni < 2; ++ni) {
    b0[ni][0] = *(const bf16x8*)&Bh[(bofs + ni * 16 + frow) * 64 + x0];
    b0[ni][1] = *(const bf16x8*)&Bh[(bofs + ni * 16 + frow) * 64 + x1];
  }
  PHASE_TOP();
#pragma unroll
  for (int kk = 0; kk < 2; ++kk)
#pragma unroll
    for (int mi = 0; mi < 4; ++mi)
#pragma unroll
      for (int ni = 0; ni < 2; ++ni)
        acc[mi][ni] = __builtin_amdgcn_mfma_f32_16x16x32_bf16(
            a0[mi][kk], b0[ni][kk], acc[mi][ni], 0, 0, 0);
  PHASE_END();

  // ---- P2: quadrant (0,1); no stage ----
#pragma unroll
  for (int ni = 0; ni < 2; ++ni) {
    b1[ni][0] = *(const bf16x8*)&Bh[(bofs + 32 + ni * 16 + frow) * 64 + x0];
    b1[ni][1] = *(const bf16x8*)&Bh[(bofs + 32 + ni * 16 + frow) * 64 + x1];
  }
  PHASE_TOP();
#pragma unroll
  for (int kk = 0; kk < 2; ++kk)
#pragma unroll
    for (int mi = 0; mi < 4; ++mi)
#pragma unroll
      for (int ni = 0; ni < 2; ++ni)
        acc[mi][2 + ni] = __builtin_amdgcn_mfma_f32_16x16x32_bf16(
            a0[mi][kk], b1[ni][kk], acc[mi][2 + ni], 0, 0, 0);
  PHASE_END();

  // ---- P3: quadrant (1,1); stage B(tau+2) (Bs[PI] dead after P2-END) ----
#pragma unroll
  for (int mi = 0; mi < 4; ++mi) {
    a1[mi][0] = *(const bf16x8*)&Ah[(64 + mi * 16 + frow) * 64 + x0];
    a1[mi][1] = *(const bf16x8*)&Ah[(64 + mi * 16 + frow) * 64 + x1];
  }
  if (kt2 < K) {
    STAGE_HALF(gB, 0,   kt2, &Bs[PI][0][0]);
    STAGE_HALF(gB, 128, kt2, &Bs[PI][1][0]);
  }
  PHASE_TOP();
#pragma unroll
  for (int kk = 0; kk < 2; ++kk)
#pragma unroll
    for (int mi = 0; mi < 4; ++mi)
#pragma unroll
      for (int ni = 0; ni < 2; ++ni)
        acc[4 + mi][2 + ni] = __builtin_amdgcn_mfma_f32_16x16x32_bf16(
            a1[mi][kk], b1[ni][kk], acc[4 + mi][2 + ni], 0, 0, 0);
  PHASE_END();

  // ---- P4: quadrant (1,0); stage A(tau+2) (As[PI] dead after P3-END) ----
  if (kt2 < K) {
    STAGE_HALF(gA, 0,   kt2, &As[PI][0][0]);
    STAGE_HALF(gA, 128, kt2, &As[PI][1][0]);
  }
  __builtin_amdgcn_s_barrier();
  __builtin_amdgcn_sched_barrier(0);
  __builtin_amdgcn_s_setprio(1);
#pragma unroll
  for (int kk = 0; kk < 2; ++kk)
#pragma unroll
    for (int mi = 0; mi < 4; ++mi)
#pragma unroll
      for (int ni = 0; ni < 2; ++ni)
        acc[4 + mi][ni] = __builtin_amdgcn_mfma_f32_16x16x32_bf16(
            a1[mi][kk], b0[ni][kk], acc[4 + mi][ni], 0, 0, 0);
  __builtin_amdgcn_s_setprio(0);
  if (kt2 < K) asm volatile("s_waitcnt vmcnt(8)" ::: "memory");
  else         asm volatile("s_waitcnt vmcnt(0)" ::: "memory");
  __builtin_amdgcn_sched_barrier(0);
  __builtin_amdgcn_s_barrier();
  __builtin_amdgcn_sched_barrier(0);
}

__device__ __forceinline__ void gemm256_body(
    const short* __restrict__ A, const short* __restrict__ B,
    const float* __restrict__ bias, float bscale, float* __restrict__ Cf,
    short* __restrict__ Cbf, int N, int K, int gm, int gn)
{
  __shared__ short As[2][2][8192];
  __shared__ short Bs[2][2][8192];
  const int t = threadIdx.x;
  const int w = t >> 6, l = t & 63;
  const int wm = w >> 2, wn = w & 3;
  const int frow = l & 15, fq = l >> 4, fr7 = l & 7;
  const int srow0 = w * 8 + (l >> 3);          // staging row within 64-group
  const int sslot = (l & 7) ^ (l >> 3);        // pre-swizzled source slot

  const short* gA = A + (long)(gm + srow0) * K + sslot * 8;
  const short* gB = B + (long)(gn + srow0) * K + sslot * 8;

  f32x4 acc[8][4] = {};

  // Prologue: full tiles 0 and 1 (16 loads); vmcnt(8) confirms tile 0.
  STAGE_HALF(gA, 0,   0,  &As[0][0][0]);
  STAGE_HALF(gA, 128, 0,  &As[0][1][0]);
  STAGE_HALF(gB, 0,   0,  &Bs[0][0][0]);
  STAGE_HALF(gB, 128, 0,  &Bs[0][1][0]);
  STAGE_HALF(gA, 0,   64, &As[1][0][0]);
  STAGE_HALF(gA, 128, 64, &As[1][1][0]);
  STAGE_HALF(gB, 0,   64, &Bs[1][0][0]);
  STAGE_HALF(gB, 128, 64, &Bs[1][1][0]);
  asm volatile("s_waitcnt vmcnt(8)" ::: "memory");  // tile0 confirmed
  __builtin_amdgcn_s_barrier();
  __builtin_amdgcn_sched_barrier(0);

  const int NT = K >> 6;  // assumed even, >= 4 (K = 1024 here)
  for (int tau = 0; tau < NT; tau += 2) {
    tile4<0>(As, Bs, gA, gB, acc, tau, K, w, wm, wn, frow, fq, fr7);
    tile4<1>(As, Bs, gA, gB, acc, tau + 1, K, w, wm, wn, frow, fq, fr7);
  }

  float bb[4];
#pragma unroll
  for (int Ni = 0; Ni < 4; ++Ni)
    bb[Ni] = bias ? bias[gn + wn * 64 + Ni * 16 + frow] * bscale : 0.f;

  // C/D layout: col = lane&15, row = (lane>>4)*4 + reg  [m89/m91]
#pragma unroll
  for (int Mi = 0; Mi < 8; ++Mi) {
#pragma unroll
    for (int r = 0; r < 4; ++r) {
      const long row = gm + wm * 128 + Mi * 16 + fq * 4 + r;
#pragma unroll
      for (int Ni = 0; Ni < 4; ++Ni) {
        const long col = gn + wn * 64 + Ni * 16 + frow;
        float v = acc[Mi][Ni][r] + bb[Ni];
        if (Cf) Cf[row * (long)N + col] = v;
        else    Cbf[row * (long)N + col] = (short)f2bf(v);
      }
    }
  }
}

__global__ __launch_bounds__(512, 2) void mfma8_abt_k(
    const short* __restrict__ A, const short* __restrict__ B,
    const float* __restrict__ bias, float bscale, float* __restrict__ Cf,
    short* __restrict__ Cbf, int N, int K, long sA, long sB, long sC,
    long sBias, int swap)
{
  const int bz = blockIdx.z;
  const int gm = (swap ? blockIdx.x : blockIdx.y) * 256;
  const int gn = (swap ? blockIdx.y : blockIdx.x) * 256;
  gemm256_body(A + (long)bz * sA, B + (long)bz * sB,
               bias ? bias + (long)bz * sBias : nullptr, bscale,
               Cf ? Cf + (long)bz * sC : nullptr,
               Cbf ? Cbf + (long)bz * sC : nullptr, N, K, gm, gn);
}

__global__ __launch_bounds__(512, 2) void mfma8_proj_k(
    const short* __restrict__ Xq, const short* __restrict__ Xk,
    const short* __restrict__ Xv, const short* __restrict__ Wq,
    const short* __restrict__ Wk, const short* __restrict__ Wv,
    const float* __restrict__ bq, const float* __restrict__ bk,
    const float* __restrict__ bv, short* __restrict__ Oq,
    short* __restrict__ Ok, short* __restrict__ Ov)
{
  const int z = blockIdx.z;
  const short* X = z == 0 ? Xq : (z == 1 ? Xk : Xv);
  const short* W = z == 0 ? Wq : (z == 1 ? Wk : Wv);
  const float* bias = z == 0 ? bq : (z == 1 ? bk : bv);
  short* O = z == 0 ? Oq : (z == 1 ? Ok : Ov);
  gemm256_body(X, W, bias, 1.0f, nullptr, O, D_MODEL, D_MODEL,
               blockIdx.x * 256, blockIdx.y * 256);
}

// ---------------- K-stats: bf16 Kp row -> bf16 pK (in place) + negent -----
__global__ __launch_bounds__(256) void kstats_k(short* __restrict__ KP,
                                                float* __restrict__ negent)
{
  __shared__ float red[4];
  const long row = blockIdx.x;
  short* x = KP + row * (long)D_MODEL;
  const int t = threadIdx.x;
  short4 raw = *(const short4*)&x[t * 4];
  float v0 = bf2f((unsigned short)raw.x), v1 = bf2f((unsigned short)raw.y);
  float v2 = bf2f((unsigned short)raw.z), v3 = bf2f((unsigned short)raw.w);
  float m = fmaxf(fmaxf(v0, v1), fmaxf(v2, v3));
  for (int o = 32; o; o >>= 1) m = fmaxf(m, __shfl_xor(m, o));
  if ((t & 63) == 0) red[t >> 6] = m;
  __syncthreads();
  m = fmaxf(fmaxf(red[0], red[1]), fmaxf(red[2], red[3]));
  __syncthreads();
  float e0 = __expf(v0 - m), e1 = __expf(v1 - m), e2 = __expf(v2 - m),
        e3 = __expf(v3 - m);
  float s = e0 + e1 + e2 + e3;
  for (int o = 32; o; o >>= 1) s += __shfl_xor(s, o);
  if ((t & 63) == 0) red[t >> 6] = s;
  __syncthreads();
  s = red[0] + red[1] + red[2] + red[3];
  __syncthreads();
  const float inv = 1.0f / s;
  const float lse = m + __logf(s);
  float p0 = e0 * inv, p1 = e1 * inv, p2 = e2 * inv, p3 = e3 * inv;
  float ne = p0 * (v0 - lse) + p1 * (v1 - lse) + p2 * (v2 - lse) +
             p3 * (v3 - lse);
  for (int o = 32; o; o >>= 1) ne += __shfl_xor(ne, o);
  if ((t & 63) == 0) red[t >> 6] = ne;
  __syncthreads();
  if (t == 0) negent[row] = red[0] + red[1] + red[2] + red[3];
  short4 pw;
  pw.x = (short)f2bf(p0); pw.y = (short)f2bf(p1);
  pw.z = (short)f2bf(p2); pw.w = (short)f2bf(p3);
  *(short4*)&x[t * 4] = pw;
}

// ---------------- attn softmax: fp32 in place + bf16 copy -----------------
__global__ __launch_bounds__(256) void asoftmax_k(float* __restrict__ S,
                                                  short* __restrict__ Sbf)
{
  __shared__ float red[4];
  const long row = blockIdx.x;
  float* x = S + row * (long)NKS;
  short* y = Sbf + row * (long)NKS;
  const int t = threadIdx.x;
  float4 v0 = *(const float4*)&x[t * 4];
  float4 v1 = *(const float4*)&x[1024 + t * 4];
  float m = fmaxf(fmaxf(fmaxf(v0.x, v0.y), fmaxf(v0.z, v0.w)),
                  fmaxf(fmaxf(v1.x, v1.y), fmaxf(v1.z, v1.w)));
  for (int o = 32; o; o >>= 1) m = fmaxf(m, __shfl_xor(m, o));
  if ((t & 63) == 0) red[t >> 6] = m;
  __syncthreads();
  m = fmaxf(fmaxf(red[0], red[1]), fmaxf(red[2], red[3]));
  __syncthreads();
  float4 e0 = {__expf(v0.x - m), __expf(v0.y - m), __expf(v0.z - m),
               __expf(v0.w - m)};
  float4 e1 = {__expf(v1.x - m), __expf(v1.y - m), __expf(v1.z - m),
               __expf(v1.w - m)};
  float s = e0.x + e0.y + e0.z + e0.w + e1.x + e1.y + e1.z + e1.w;
  for (int o = 32; o; o >>= 1) s += __shfl_xor(s, o);
  if ((t & 63) == 0) red[t >> 6] = s;
  __syncthreads();
  s = red[0] + red[1] + red[2] + red[3];
  const float inv = 1.0f / s;
  float4 p0 = {e0.x * inv, e0.y * inv, e0.z * inv, e0.w * inv};
  float4 p1 = {e1.x * inv, e1.y * inv, e1.z * inv, e1.w * inv};
  *(float4*)&x[t * 4] = p0;
  *(float4*)&x[1024 + t * 4] = p1;
  short4 b0, b1;
  b0.x = (short)f2bf(p0.x); b0.y = (short)f2bf(p0.y);
  b0.z = (short)f2bf(p0.z); b0.w = (short)f2bf(p0.w);
  b1.x = (short)f2bf(p1.x); b1.y = (short)f2bf(p1.y);
  b1.z = (short)f2bf(p1.z); b1.w = (short)f2bf(p1.w);
  *(short4*)&y[t * 4] = b0;
  *(short4*)&y[1024 + t * 4] = b1;
}

// ---------------- Vp [8192,1024] -> Vpt [B][1024][2048] transpose ---------
__global__ __launch_bounds__(256) void transpose_k(const short* __restrict__ src,
                                                   short* __restrict__ dst)
{
  __shared__ short tile[64][68];
  const int j0 = blockIdx.x * 64;
  const int d0 = blockIdx.y * 64;
  const int t = threadIdx.x;
  const int r = t >> 2, c = t & 3;
#pragma unroll
  for (int i = 0; i < 4; ++i)
    *(short4*)&tile[r][c * 16 + i * 4] =
        *(const short4*)&src[(long)(j0 + r) * D_MODEL + d0 + c * 16 + i * 4];
  __syncthreads();
  const long b = j0 >> 11;
  const int jj = j0 & 2047;
#pragma unroll
  for (int i = 0; i < 4; ++i) {
    short4 o;
    o.x = tile[c * 16 + i * 4 + 0][r];
    o.y = tile[c * 16 + i * 4 + 1][r];
    o.z = tile[c * 16 + i * 4 + 2][r];
    o.w = tile[c * 16 + i * 4 + 3][r];
    *(short4*)&dst[b * ((long)D_MODEL * NKS) + (long)(d0 + r) * NKS + jj +
                   c * 16 + i * 4] = o;
  }
}

extern "C" void kernel_launch(void* const* d_in, const int* in_sizes, int n_in,
                              void* d_out, int out_size, void* d_ws,
                              size_t ws_size, hipStream_t stream)
{
  const float* Q = (const float*)d_in[0];
  const float* K = (const float*)d_in[1];
  const float* V = (const float*)d_in[2];
  const float* Wq = (const float*)d_in[3];
  const float* bq = (const float*)d_in[4];
  const float* Wk = (const float*)d_in[5];
  const float* bk = (const float*)d_in[6];
  const float* Wv = (const float*)d_in[7];
  const float* bv = (const float*)d_in[8];

  float* out = (float*)d_out;                         // [B,NQ,D] fp32
  float* attn = out + (long)BATCH * NQS * D_MODEL;    // [B,NQ,NK] fp32

  const long SZ = (long)BATCH * NQS * D_MODEL;        // 8388608 elements
  short* ws = (short*)d_ws;
  short* Qbf = ws;              // S0 (dead after proj) -> attn_bf low half
  short* Kbf = ws + SZ;         // S1 (dead after proj) -> attn_bf high half
  short* Vbf = ws + 2 * SZ;     // S2 (dead after proj) -> Vpt
  short* Qp  = ws + 3 * SZ;     // S3
  short* pK  = ws + 4 * SZ;     // S4 (Kp -> pK in place)
  short* Vp  = ws + 5 * SZ;     // S5
  float* negent = (float*)(ws + 6 * SZ);              // [B*NK] fp32
  short* attn_bf = ws;          // S0+S1 reuse
  short* Vpt = ws + 2 * SZ;     // S2 reuse: [B][D][NK]

  // bf16 weights live in d_out's attn region (dead until scores GEMM).
  short* Wqb = (short*)attn;
  short* Wkb = Wqb + (long)D_MODEL * D_MODEL;
  short* Wvb = Wkb + (long)D_MODEL * D_MODEL;

  dim3 blk(256), blk8(512);
  const int n8x = (int)(SZ / 8);                  // 1048576
  const int n8w = D_MODEL * D_MODEL / 8;          // 131072

  // 1) converts (2 dispatches)
  cvt3_k<<<dim3(n8x / 256, 1, 3), blk, 0, stream>>>(Q, K, V, Qbf, Kbf, Vbf,
                                                    n8x);
  cvt3_k<<<dim3(n8w / 256, 1, 3), blk, 0, stream>>>(Wq, Wk, Wv, Wqb, Wkb, Wvb,
                                                    n8w);

  // 2) projections, 256x256 8-phase: grid (32, 4, 3)
  dim3 gp((BATCH * NQS) / 256, D_MODEL / 256, 3);
  mfma8_proj_k<<<gp, blk8, 0, stream>>>(Qbf, Kbf, Vbf, Wqb, Wkb, Wvb, bq, bk,
                                        bv, Qp, pK, Vp);

  // 3) Kp -> pK + negent
  kstats_k<<<dim3(BATCH * NKS), blk, 0, stream>>>(pK, negent);

  // 4) Vp -> Vpt
  transpose_k<<<dim3((BATCH * NKS) / 64, D_MODEL / 64), blk, 0, stream>>>(Vp,
                                                                          Vpt);

  // 5) scores = Qp·pK^T - negent[col] -> attn fp32 (256² 8-phase; 256 blocks)
  dim3 gs(NKS / 256, NQS / 256, BATCH);
  mfma8_abt_k<<<gs, blk8, 0, stream>>>(
      Qp, pK, negent, -1.0f, attn, nullptr, NKS, D_MODEL,
      (long)NQS * D_MODEL, (long)NKS * D_MODEL, (long)NQS * NKS, NKS, 0);

  // 6) attn = softmax(scores) fp32 in place + bf16 copy
  asoftmax_k<<<dim3(BATCH * NQS), blk, 0, stream>>>(attn, attn_bf);

  // 7) out = attn_bf · Vpt^T, 128² m-major: grid (16, 8, 4)
  dim3 go(NQS / 128, D_MODEL / 128, BATCH);
  mfma_abt_k<<<go, blk, 0, stream>>>(
      attn_bf, Vpt, nullptr, 0.f, out, nullptr, D_MODEL, NKS,
      (long)NQS * NKS, (long)D_MODEL * NKS, (long)NQS * D_MODEL, 0, 1);
}